// Round 8
// baseline (255.926 us; speedup 1.0000x reference)
//
#include <hip/hip_runtime.h>
#include <cmath>

#define BB 8
#define LLEN 1024
#define CC 256
#define NH 8
#define HD 32
#define IMG 32
#define EPSBN 1e-5f
#define QSCALE 0.0625f   // 256^-0.5
#define SCLOG2E 0.09016844005556f  // QSCALE * log2(e), folded into Q

typedef short bf16x8 __attribute__((ext_vector_type(8)));
typedef short bf16x4 __attribute__((ext_vector_type(4)));
typedef float f32x4 __attribute__((ext_vector_type(4)));

static __device__ __forceinline__ unsigned short f2bf(float v) {
  union { float f; unsigned u; } a; a.f = v;
  unsigned r = a.u + 0x7fff + ((a.u >> 16) & 1);  // RNE
  return (unsigned short)(r >> 16);
}
static __device__ __forceinline__ float bf2f(unsigned short s) {
  union { unsigned u; float f; } a; a.u = ((unsigned)s) << 16; return a.f;
}

// ---------------- merged prep: x/y -> bf16 planes, conv W repack, Wo hi/lo ----------------
// grid 5120: [0,4096) xy planes, [4096,4864) conv weights, [4864,5120) Wo
__global__ __launch_bounds__(256) void k_prep(const float* __restrict__ x,
                                              const float* __restrict__ y,
                                              const float* __restrict__ w0,
                                              const float* __restrict__ w1,
                                              const float* __restrict__ w2,
                                              const float* __restrict__ Wo,
                                              short* __restrict__ xh,
                                              short* __restrict__ yh,
                                              short* __restrict__ Wrh,
                                              short* __restrict__ Woh,
                                              short* __restrict__ Wol) {
  int bid = blockIdx.x;
  if (bid < 4096) {
    const float* s = bid >= 2048 ? y : x;
    short* d = bid >= 2048 ? yh : xh;
    size_t i = (size_t)((bid & 2047) << 8) + threadIdx.x;  // float4 index
    float4 v = ((const float4*)s)[i];
    bf16x4 o;
    o[0] = (short)f2bf(v.x); o[1] = (short)f2bf(v.y);
    o[2] = (short)f2bf(v.z); o[3] = (short)f2bf(v.w);
    *(bf16x4*)(d + i * 4) = o;
  } else if (bid < 4864) {
    int k = bid - 4096;
    int t = k >> 8, co = k & 255, ci = threadIdx.x;
    const float* w = t == 0 ? w0 : (t == 1 ? w1 : w2);
    const float* src = w + ((size_t)co * CC + ci) * 9;
    size_t ob = (size_t)t * 9 * 65536;
#pragma unroll
    for (int tap = 0; tap < 9; ++tap)
      Wrh[ob + (size_t)(tap * CC + co) * CC + ci] = (short)f2bf(src[tap]);
  } else {
    int i = ((bid - 4864) << 8) + threadIdx.x;
    float v = Wo[i];
    unsigned short h = f2bf(v);
    Woh[i] = (short)h;
    Wol[i] = (short)f2bf(v - bf2f(h));
  }
}

// ---------------- conv3x3 MFMA v3: weights direct-from-global, input in LDS ----------------
// grid (co-tiles 4, strips 4, 24=tensor*8+b), block 256 (4 waves).
// All 4 waves use identical B-frags (16B contiguous in Wrh) -> global load,
// L1-broadcast; no weight LDS staging, no 8-way-conflict sW reads.
__global__ __launch_bounds__(256, 3) void k_conv(const short* __restrict__ xh,
                                                 const short* __restrict__ yh,
                                                 const short* __restrict__ Wrh,
                                                 short* __restrict__ ch,
                                                 float* __restrict__ st) {
  __shared__ __align__(16) short sI[340 * 32];      // [padded sp 10x34][ci 32] swizzled
  __shared__ float sws[4][64];
  __shared__ float swq[4][64];

  int tid = threadIdx.x;
  int co0 = blockIdx.x << 6;
  int r0 = blockIdx.y << 3;            // first of 8 image rows
  int z = blockIdx.z;
  int t = z >> 3, b = z & 7;
  const short* inb = (t == 0 ? xh : yh) + (size_t)b * LLEN * CC;
  const short* wb = Wrh + (size_t)t * 9 * 65536;

  int lane = tid & 63, w = tid >> 6;
  int quad = lane >> 4, mm = lane & 15;

  int pbA[4];
#pragma unroll
  for (int mt = 0; mt < 4; ++mt) {
    int sp = w * 64 + mt * 16 + mm;
    pbA[mt] = (sp >> 5) * 34 + (sp & 31);
  }
  const int dtap[9] = {0, 1, 2, 34, 35, 36, 68, 69, 70};

  const short* wbase = wb + (size_t)(co0 + mm) * CC + quad * 8;

  f32x4 acc[4][4];
#pragma unroll
  for (int mt = 0; mt < 4; ++mt)
#pragma unroll
    for (int nt = 0; nt < 4; ++nt) acc[mt][nt] = (f32x4){0.f, 0.f, 0.f, 0.f};

  for (int kc = 0; kc < 8; ++kc) {
    int ci0 = kc << 5;
    __syncthreads();
#pragma unroll
    for (int j = 0; j < 6; ++j) {
      int idx = tid + (j << 8);
      if (idx < 1360) {
        int sp_p = idx >> 2, cg = idx & 3;
        int pr = sp_p / 34;
        int px = sp_p - pr * 34;
        int ir = r0 - 1 + pr;
        int xx = px - 1;
        bf16x8 v = {0, 0, 0, 0, 0, 0, 0, 0};
        if (ir >= 0 && ir < IMG && xx >= 0 && xx < IMG)
          v = *(const bf16x8*)(inb + (size_t)(ir * 32 + xx) * CC + ci0 + cg * 8);
        *(bf16x8*)(sI + sp_p * 32 + ((cg ^ (sp_p & 3)) << 3)) = v;
      }
    }
    __syncthreads();

    const short* wk0 = wbase + ci0;
#pragma unroll
    for (int tap = 0; tap < 9; ++tap) {
      bf16x8 Bw[4];
#pragma unroll
      for (int nt = 0; nt < 4; ++nt)
        Bw[nt] = *(const bf16x8*)(wk0 + (size_t)tap * 65536 + nt * 4096);
      bf16x8 Af[4];
#pragma unroll
      for (int mt = 0; mt < 4; ++mt) {
        int sp_p = pbA[mt] + dtap[tap];
        Af[mt] = *(const bf16x8*)(sI + sp_p * 32 + ((quad ^ (sp_p & 3)) << 3));
      }
#pragma unroll
      for (int mt = 0; mt < 4; ++mt)
#pragma unroll
        for (int nt = 0; nt < 4; ++nt)
          acc[mt][nt] = __builtin_amdgcn_mfma_f32_16x16x32_bf16(Af[mt], Bw[nt],
                                                                acc[mt][nt], 0, 0, 0);
    }
  }

  size_t tb = (size_t)t * 8192 + b * 1024 + r0 * 32;
#pragma unroll
  for (int mt = 0; mt < 4; ++mt)
#pragma unroll
    for (int nt = 0; nt < 4; ++nt)
#pragma unroll
      for (int r = 0; r < 4; ++r) {
        int sp = w * 64 + mt * 16 + quad * 4 + r;
        ch[(tb + sp) * CC + co0 + nt * 16 + mm] = (short)f2bf(acc[mt][nt][r]);
      }

  float s[4], q[4];
#pragma unroll
  for (int nt = 0; nt < 4; ++nt) {
    float ss = 0.f, qq = 0.f;
#pragma unroll
    for (int mt = 0; mt < 4; ++mt)
#pragma unroll
      for (int r = 0; r < 4; ++r) {
        float v = acc[mt][nt][r];
        ss += v;
        qq += v * v;
      }
    ss += __shfl_xor(ss, 16); ss += __shfl_xor(ss, 32);
    qq += __shfl_xor(qq, 16); qq += __shfl_xor(qq, 32);
    s[nt] = ss; q[nt] = qq;
  }
  if (quad == 0) {
#pragma unroll
    for (int nt = 0; nt < 4; ++nt) {
      sws[w][nt * 16 + mm] = s[nt];
      swq[w][nt * 16 + mm] = q[nt];
    }
  }
  __syncthreads();
  if (tid < 64) {
    float S = sws[0][tid] + sws[1][tid] + sws[2][tid] + sws[3][tid];
    float Q = swq[0][tid] + swq[1][tid] + swq[2][tid] + swq[3][tid];
    atomicAdd(&st[t * 512 + co0 + tid], S);
    atomicAdd(&st[t * 512 + 256 + co0 + tid], Q);
  }
}

// ---------------- fold BN into proj weights -> bf16 hi/lo + fp32 bias ----------------
__global__ __launch_bounds__(256) void k_fuse(const float* __restrict__ Wq,
                                              const float* __restrict__ Wk,
                                              const float* __restrict__ Wv,
                                              const float* __restrict__ gq,
                                              const float* __restrict__ gk,
                                              const float* __restrict__ gv,
                                              const float* __restrict__ bq,
                                              const float* __restrict__ bk,
                                              const float* __restrict__ bv,
                                              const float* __restrict__ st,
                                              short* __restrict__ Wfh,
                                              short* __restrict__ Wfl,
                                              float* __restrict__ bfv) {
  int t = blockIdx.y;
  const float* W = t == 0 ? Wq : (t == 1 ? Wk : Wv);
  const float* gamma = t == 0 ? gq : (t == 1 ? gk : gv);
  const float* beta = t == 0 ? bq : (t == 1 ? bk : bv);
  int co = blockIdx.x, ci = threadIdx.x;
  float mu = st[t * 512 + ci] * (1.f / 8192.f);
  float var = st[t * 512 + 256 + ci] * (1.f / 8192.f) - mu * mu;
  float a = gamma[ci] * rsqrtf(var + EPSBN);
  float dt = beta[ci] - mu * a;
  float wv = W[co * CC + ci];
  float v = wv * a;
  unsigned short hh = f2bf(v);
  Wfh[(size_t)t * 65536 + co * CC + ci] = (short)hh;
  Wfl[(size_t)t * 65536 + co * CC + ci] = (short)f2bf(v - bf2f(hh));
  __shared__ float red[256];
  red[ci] = dt * wv;
  __syncthreads();
  for (int s2 = 128; s2 > 0; s2 >>= 1) {
    if (ci < s2) red[ci] += red[ci + s2];
    __syncthreads();
  }
  if (ci == 0) bfv[t * 256 + co] = red[0];
}

// ---------------- projections (fused q/k/v), register-stationary B ----------------
__global__ __launch_bounds__(256, 2) void k_proj(const short* __restrict__ ch,
                                                 const short* __restrict__ Wfh,
                                                 const short* __restrict__ Wfl,
                                                 const float* __restrict__ bfv,
                                                 short* __restrict__ Qh,
                                                 short* __restrict__ Kh,
                                                 short* __restrict__ Vh) {
  __shared__ __align__(16) short sT[64 * 264];   // V transpose buffer [co][tok'+pad]
  int tid = threadIdx.x;
  int t = blockIdx.z;
  int t0 = blockIdx.x << 8;
  int co0 = blockIdx.y << 6;
  int lane = tid & 63, w = tid >> 6;
  int quad = lane >> 4, mm = lane & 15;
  int colw = co0 + w * 16;
  const short* cht = ch + (size_t)t * 8192 * CC;

  bf16x8 Bh[8], Bl[8];
  {
    const short* bh = Wfh + (size_t)t * 65536 + (size_t)(colw + mm) * CC + quad * 8;
    const short* bl = Wfl + (size_t)t * 65536 + (size_t)(colw + mm) * CC + quad * 8;
#pragma unroll
    for (int kc = 0; kc < 8; ++kc) {
      Bh[kc] = *(const bf16x8*)(bh + kc * 32);
      Bl[kc] = *(const bf16x8*)(bl + kc * 32);
    }
  }
  float bv = bfv[t * 256 + colw + mm];

  bf16x8 A0[8], A1[8];
  auto loadA = [&](bf16x8* dst, int g) {
    const short* a = cht + (size_t)(t0 + g * 16 + mm) * CC + quad * 8;
#pragma unroll
    for (int kc = 0; kc < 8; ++kc) dst[kc] = *(const bf16x8*)(a + kc * 32);
  };
  auto compute = [&](const bf16x8* A, int g) {
    f32x4 aH = {0.f, 0.f, 0.f, 0.f}, aL = {0.f, 0.f, 0.f, 0.f};
#pragma unroll
    for (int kc = 0; kc < 8; ++kc) {
      aH = __builtin_amdgcn_mfma_f32_16x16x32_bf16(A[kc], Bh[kc], aH, 0, 0, 0);
      aL = __builtin_amdgcn_mfma_f32_16x16x32_bf16(A[kc], Bl[kc], aL, 0, 0, 0);
    }
    if (t == 0) {
#pragma unroll
      for (int r = 0; r < 4; ++r) {
        int token = t0 + g * 16 + quad * 4 + r;
        Qh[(size_t)token * CC + colw + mm] =
            (short)f2bf((aH[r] + aL[r] + bv) * SCLOG2E);
      }
    } else if (t == 1) {
#pragma unroll
      for (int r = 0; r < 4; ++r) {
        int token = t0 + g * 16 + quad * 4 + r;
        Kh[(size_t)token * CC + colw + mm] = (short)f2bf(aH[r] + aL[r] + bv);
      }
    } else {
      // t' = 16*quad + 4*r + (g&3) within 64-block (g>>2)
#pragma unroll
      for (int r = 0; r < 4; ++r)
        sT[(w * 16 + mm) * 264 + (g >> 2) * 64 + 16 * quad + 4 * r + (g & 3)] =
            (short)f2bf(aH[r] + aL[r] + bv);
    }
  };

  loadA(A0, 0);
#pragma unroll
  for (int g = 0; g < 16; g += 2) {
    loadA(A1, g + 1);
    compute(A0, g);
    if (g + 2 < 16) loadA(A0, g + 2);
    compute(A1, g + 1);
  }

  if (t == 2) {
    __syncthreads();
    int b = t0 >> 10, l0 = t0 & 1023;
#pragma unroll
    for (int j = 0; j < 8; ++j) {
      int idx = tid + (j << 8);          // 2048 = 64 co x 32 tok-groups
      int co = idx >> 5, tg = idx & 31;
      bf16x8 v = *(const bf16x8*)(sT + co * 264 + tg * 8);
      *(bf16x8*)(Vh + ((size_t)(b * CC) + co0 + co) * LLEN + l0 + tg * 8) = v;
    }
  }
}

// ---------------- flash attention v4: K/V ping-pong double-buffer ----------------
// grid (64 = b*8+h, 8 q-tiles), block 256: 4 waves x 32 q-rows = 128 q-rows.
// Tile t+1's global loads issue before tile t's compute; store lands after the
// post-compute barrier -> VMEM latency hidden behind MFMA/VALU.
__global__ __launch_bounds__(256, 2) void k_attn(const short* __restrict__ Qh,
                                                 const short* __restrict__ Kh,
                                                 const short* __restrict__ Vh,
                                                 short* __restrict__ AOh) {
  __shared__ __align__(16) short sK[2][64 * 32];   // [t][d]
  __shared__ __align__(16) short sV[2][32 * 72];   // [d][t'] stride 72
  __shared__ __align__(16) short sP[4 * 32 * 72];  // per-wave [q][t'] stride 72

  int tid = threadIdx.x;
  int lane = tid & 63, w = tid >> 6;
  int quad = lane >> 4, mm = lane & 15;
  int bh = blockIdx.x;
  int b = bh >> 3, h = bh & 7;
  int l0 = blockIdx.y << 7;

  bf16x8 qf[2];
#pragma unroll
  for (int mf = 0; mf < 2; ++mf)
    qf[mf] = *(const bf16x8*)(Qh + ((size_t)(b * LLEN) + l0 + w * 32 + mf * 16 + mm) * CC +
                              h * HD + quad * 8);

  f32x4 accO[2][2], accL[2];
#pragma unroll
  for (int mf = 0; mf < 2; ++mf) {
    accO[mf][0] = (f32x4){0.f, 0.f, 0.f, 0.f};
    accO[mf][1] = (f32x4){0.f, 0.f, 0.f, 0.f};
    accL[mf] = (f32x4){0.f, 0.f, 0.f, 0.f};
  }
  bf16x8 ones;
#pragma unroll
  for (int j = 0; j < 8; ++j) ones[j] = (short)0x3F80;  // bf16 1.0

  int kt = tid >> 2, kc4 = tid & 3;
  const short* kgp = Kh + ((size_t)(b * LLEN) + kt) * CC + h * HD + kc4 * 8;
  int kofs = kt * 32 + kc4 * 8;
  int vd = tid >> 3, vt8 = tid & 7;
  const short* vgp = Vh + ((size_t)(b * CC) + h * HD + vd) * LLEN + vt8 * 8;
  int vofs = vd * 72 + vt8 * 8;
  short* pw = sP + w * (32 * 72);

  bf16x8 kr = *(const bf16x8*)kgp;
  bf16x8 vr = *(const bf16x8*)vgp;
  *(bf16x8*)(sK[0] + kofs) = kr;
  *(bf16x8*)(sV[0] + vofs) = vr;
  __syncthreads();

  for (int tt = 0; tt < 16; ++tt) {
    if (tt < 15) {
      kr = *(const bf16x8*)(kgp + (size_t)(tt + 1) * 64 * CC);
      vr = *(const bf16x8*)(vgp + (tt + 1) * 64);
    }
    const short* sKc = sK[tt & 1];
    const short* sVc = sV[tt & 1];

#pragma unroll
    for (int mf = 0; mf < 2; ++mf) {
      f32x4 accS[4];
#pragma unroll
      for (int nt = 0; nt < 4; ++nt) {
        bf16x8 kf = *(const bf16x8*)(sKc + (nt * 16 + mm) * 32 + quad * 8);
        f32x4 z = {0.f, 0.f, 0.f, 0.f};
        accS[nt] = __builtin_amdgcn_mfma_f32_16x16x32_bf16(qf[mf], kf, z, 0, 0, 0);
      }
      // P[q][t'] with t' = 4*mm + nt: one b64 write per row
#pragma unroll
      for (int r = 0; r < 4; ++r) {
        int q = mf * 16 + quad * 4 + r;
        bf16x4 pk;
#pragma unroll
        for (int nt = 0; nt < 4; ++nt) {
          union { float f; unsigned u; } cv;
          cv.f = __builtin_exp2f(accS[nt][r]);
          pk[nt] = (short)((cv.u + 0x8000u) >> 16);  // round-half-up bf16
        }
        *(bf16x4*)(pw + q * 72 + mm * 4) = pk;
      }
    }

#pragma unroll
    for (int kc = 0; kc < 2; ++kc) {
      bf16x8 vf0 = *(const bf16x8*)(sVc + mm * 72 + kc * 32 + quad * 8);
      bf16x8 vf1 = *(const bf16x8*)(sVc + (16 + mm) * 72 + kc * 32 + quad * 8);
#pragma unroll
      for (int mf = 0; mf < 2; ++mf) {
        bf16x8 pf = *(const bf16x8*)(pw + (mf * 16 + mm) * 72 + kc * 32 + quad * 8);
        accL[mf] = __builtin_amdgcn_mfma_f32_16x16x32_bf16(pf, ones, accL[mf], 0, 0, 0);
        accO[mf][0] = __builtin_amdgcn_mfma_f32_16x16x32_bf16(pf, vf0, accO[mf][0], 0, 0, 0);
        accO[mf][1] = __builtin_amdgcn_mfma_f32_16x16x32_bf16(pf, vf1, accO[mf][1], 0, 0, 0);
      }
    }

    if (tt < 15) {
      __syncthreads();  // all waves done reading buffer (tt+1)&1 (from tile tt-1)
      *(bf16x8*)(sK[(tt + 1) & 1] + kofs) = kr;
      *(bf16x8*)(sV[(tt + 1) & 1] + vofs) = vr;
      __syncthreads();
    }
  }

#pragma unroll
  for (int mf = 0; mf < 2; ++mf)
#pragma unroll
    for (int r = 0; r < 4; ++r) {
      float inv = __builtin_amdgcn_rcpf(accL[mf][r]);
      size_t token = (size_t)(b * LLEN) + l0 + w * 32 + mf * 16 + quad * 4 + r;
      AOh[token * CC + h * HD + mm] = (short)f2bf(accO[mf][0][r] * inv);
      AOh[token * CC + h * HD + 16 + mm] = (short)f2bf(accO[mf][1][r] * inv);
    }
}

// ---------------- output GEMM, register-stationary B, fp32 out ----------------
__global__ __launch_bounds__(256, 2) void k_out(const short* __restrict__ AOh,
                                                const short* __restrict__ Woh,
                                                const short* __restrict__ Wol,
                                                const float* __restrict__ bo,
                                                float* __restrict__ out) {
  int tid = threadIdx.x;
  int t0 = blockIdx.x << 7;
  int co0 = blockIdx.y << 6;
  int lane = tid & 63, w = tid >> 6;
  int quad = lane >> 4, mm = lane & 15;
  int colw = co0 + w * 16;

  bf16x8 Bh[8], Bl[8];
  {
    const short* bh = Woh + (size_t)(colw + mm) * CC + quad * 8;
    const short* bl = Wol + (size_t)(colw + mm) * CC + quad * 8;
#pragma unroll
    for (int kc = 0; kc < 8; ++kc) {
      Bh[kc] = *(const bf16x8*)(bh + kc * 32);
      Bl[kc] = *(const bf16x8*)(bl + kc * 32);
    }
  }
  float bv = bo[colw + mm];

  bf16x8 A0[8], A1[8];
  auto loadA = [&](bf16x8* dst, int g) {
    const short* a = AOh + (size_t)(t0 + g * 16 + mm) * CC + quad * 8;
#pragma unroll
    for (int kc = 0; kc < 8; ++kc) dst[kc] = *(const bf16x8*)(a + kc * 32);
  };
  auto compute = [&](const bf16x8* A, int g) {
    f32x4 aH = {0.f, 0.f, 0.f, 0.f}, aL = {0.f, 0.f, 0.f, 0.f};
#pragma unroll
    for (int kc = 0; kc < 8; ++kc) {
      aH = __builtin_amdgcn_mfma_f32_16x16x32_bf16(A[kc], Bh[kc], aH, 0, 0, 0);
      aL = __builtin_amdgcn_mfma_f32_16x16x32_bf16(A[kc], Bl[kc], aL, 0, 0, 0);
    }
#pragma unroll
    for (int r = 0; r < 4; ++r) {
      int token = t0 + g * 16 + quad * 4 + r;
      out[(size_t)token * CC + colw + mm] = aH[r] + aL[r] + bv;
    }
  };

  loadA(A0, 0);
#pragma unroll
  for (int g = 0; g < 8; g += 2) {
    loadA(A1, g + 1);
    compute(A0, g);
    if (g + 2 < 8) loadA(A0, g + 2);
    compute(A1, g + 1);
  }
}

extern "C" void kernel_launch(void* const* d_in, const int* in_sizes, int n_in,
                              void* d_out, int out_size, void* d_ws, size_t ws_size,
                              hipStream_t stream) {
  (void)in_sizes; (void)n_in; (void)out_size; (void)ws_size;
  const float* x  = (const float*)d_in[0];
  const float* y  = (const float*)d_in[1];
  const float* wq = (const float*)d_in[4];
  const float* gq = (const float*)d_in[5];
  const float* bq = (const float*)d_in[6];
  const float* wk = (const float*)d_in[7];
  const float* gk = (const float*)d_in[8];
  const float* bk = (const float*)d_in[9];
  const float* wv = (const float*)d_in[10];
  const float* gv = (const float*)d_in[11];
  const float* bv = (const float*)d_in[12];
  const float* Wq = (const float*)d_in[13];
  const float* Wk = (const float*)d_in[14];
  const float* Wv = (const float*)d_in[15];
  const float* Wo = (const float*)d_in[16];
  const float* bo = (const float*)d_in[17];
  float* out = (float*)d_out;

  const size_t NP = (size_t)8192 * 256;  // one bf16 plane = 2M shorts
  short* xh  = (short*)d_ws;
  short* yh  = xh + NP;
  short* ch  = yh + NP;            // conv-hi [3] planes
  short* Qh  = ch + 3 * NP;
  short* Kh  = Qh + NP;
  short* Vh  = Kh + NP;
  short* AOh = Vh + NP;
  short* Wrh = AOh + NP;           // [3][9][256][256]
  short* Wfh = Wrh + (size_t)3 * 9 * 65536;
  short* Wfl = Wfh + 3 * 65536;
  short* Woh = Wfl + 3 * 65536;
  short* Wol = Woh + 65536;
  float* st  = (float*)(Wol + 65536);  // 3 x (sum256 + sumsq256)
  float* bfv = st + 1536;              // 3 x 256 fused bias

  hipMemsetAsync(st, 0, 1536 * sizeof(float), stream);

  k_prep<<<5120, 256, 0, stream>>>(x, y, wq, wk, wv, Wo, xh, yh, Wrh, Woh, Wol);

  k_conv<<<dim3(4, 4, 24), 256, 0, stream>>>(xh, yh, Wrh, ch, st);

  k_fuse<<<dim3(256, 3), 256, 0, stream>>>(Wq, Wk, Wv, gq, gk, gv, bq, bk, bv,
                                           st, Wfh, Wfl, bfv);

  k_proj<<<dim3(32, 4, 3), 256, 0, stream>>>(ch, Wfh, Wfl, bfv, Qh, Kh, Vh);

  k_attn<<<dim3(64, 8), 256, 0, stream>>>(Qh, Kh, Vh, AOh);

  k_out<<<dim3(64, 4), 256, 0, stream>>>(AOh, Woh, Wol, bo, out);
}

// Round 9
// 217.800 us; speedup vs baseline: 1.1751x; 1.1751x over previous
//
#include <hip/hip_runtime.h>
#include <cmath>

#define BB 8
#define LLEN 1024
#define CC 256
#define NH 8
#define HD 32
#define IMG 32
#define EPSBN 1e-5f
#define QSCALE 0.0625f   // 256^-0.5
#define SCLOG2E 0.09016844005556f  // QSCALE * log2(e), folded into Q

typedef short bf16x8 __attribute__((ext_vector_type(8)));
typedef short bf16x4 __attribute__((ext_vector_type(4)));
typedef float f32x4 __attribute__((ext_vector_type(4)));

static __device__ __forceinline__ unsigned short f2bf(float v) {
  union { float f; unsigned u; } a; a.f = v;
  unsigned r = a.u + 0x7fff + ((a.u >> 16) & 1);  // RNE
  return (unsigned short)(r >> 16);
}
static __device__ __forceinline__ float bf2f(unsigned short s) {
  union { unsigned u; float f; } a; a.u = ((unsigned)s) << 16; return a.f;
}

// ---------------- merged prep ----------------
// grid 5120: [0,4096) xy planes, [4096,4864) conv weights (fragment-major pack),
// [4864,5120) Wo hi/lo.
// Wp layout: [t][cb 4][kc 8][tap 9][nt 4][lane 64][8] -- one wave b128 load
// per fragment is 1KB fully contiguous.
__global__ __launch_bounds__(256) void k_prep(const float* __restrict__ x,
                                              const float* __restrict__ y,
                                              const float* __restrict__ w0,
                                              const float* __restrict__ w1,
                                              const float* __restrict__ w2,
                                              const float* __restrict__ Wo,
                                              short* __restrict__ xh,
                                              short* __restrict__ yh,
                                              short* __restrict__ Wp,
                                              short* __restrict__ Woh,
                                              short* __restrict__ Wol) {
  int bid = blockIdx.x;
  if (bid < 4096) {
    const float* s = bid >= 2048 ? y : x;
    short* d = bid >= 2048 ? yh : xh;
    size_t i = (size_t)((bid & 2047) << 8) + threadIdx.x;  // float4 index
    float4 v = ((const float4*)s)[i];
    bf16x4 o;
    o[0] = (short)f2bf(v.x); o[1] = (short)f2bf(v.y);
    o[2] = (short)f2bf(v.z); o[3] = (short)f2bf(v.w);
    *(bf16x4*)(d + i * 4) = o;
  } else if (bid < 4864) {
    int k = bid - 4096;
    int t = k >> 8, co = k & 255, ci = threadIdx.x;
    const float* w = t == 0 ? w0 : (t == 1 ? w1 : w2);
    const float* src = w + ((size_t)co * CC + ci) * 9;
    int cb = co >> 6, nt = (co >> 4) & 3, mmw = co & 15;
    int kcw = ci >> 5, quadw = (ci >> 3) & 3, e = ci & 7;
    int lanew = quadw * 16 + mmw;
    size_t base = ((size_t)(t * 4 + cb) * 8 + kcw) * 9;
#pragma unroll
    for (int tap = 0; tap < 9; ++tap)
      Wp[((base + tap) * 4 + nt) * 512 + lanew * 8 + e] = (short)f2bf(src[tap]);
  } else {
    int i = ((bid - 4864) << 8) + threadIdx.x;
    float v = Wo[i];
    unsigned short h = f2bf(v);
    Woh[i] = (short)h;
    Wol[i] = (short)f2bf(v - bf2f(h));
  }
}

// ---------------- conv3x3 MFMA v5 ----------------
// grid (co-tiles 4, strips 8, 24=tensor*8+b), block 256 (4 waves), 3 blocks/CU.
// Block: 64 co x 128 sp (4 image rows). Wave: 32 sp x 64 co (2 mt x 4 nt).
// Weights: packed-fragment global loads, register double-buffered 1 tap ahead.
// Input: LDS halo tile (6x34 padded rows), register-prefetched 1 chunk ahead,
// swizzle (g + (sp_p>>1))&3 -> 2-way (free) fragment reads.
__global__ __launch_bounds__(256, 3) void k_conv(const short* __restrict__ xh,
                                                 const short* __restrict__ yh,
                                                 const short* __restrict__ Wp,
                                                 short* __restrict__ ch,
                                                 float* __restrict__ st) {
  __shared__ __align__(16) short sI[204 * 32];
  __shared__ float sws[4][64];
  __shared__ float swq[4][64];

  int tid = threadIdx.x;
  int cb = blockIdx.x;
  int co0 = cb << 6;
  int r0 = blockIdx.y << 2;            // 4 image rows
  int z = blockIdx.z;
  int t = z >> 3, b = z & 7;
  const short* inb = (t == 0 ? xh : yh) + (size_t)b * LLEN * CC;

  int lane = tid & 63, w = tid >> 6;
  int quad = lane >> 4, mm = lane & 15;

  int pbA[2];
#pragma unroll
  for (int mt = 0; mt < 2; ++mt) {
    int sp = w * 32 + mt * 16 + mm;
    pbA[mt] = (sp >> 5) * 34 + (sp & 31);
  }
  const int dtap[9] = {0, 1, 2, 34, 35, 36, 68, 69, 70};

  // staging geometry (4 b128 per thread, 816 total)
  bool ivalid[4], iact[4];
  int ioff[4], sidx[4];
#pragma unroll
  for (int j = 0; j < 4; ++j) {
    int idx = tid + (j << 8);
    ivalid[j] = idx < 816;
    int sp_p = idx >> 2, cg = idx & 3;
    int pr = sp_p / 34;
    int px = sp_p - pr * 34;
    int ir = r0 - 1 + pr;
    int xx = px - 1;
    iact[j] = ivalid[j] && (ir >= 0) && (ir < IMG) && (xx >= 0) && (xx < IMG);
    ioff[j] = ((ir < 0 ? 0 : ir) * 32 + (xx < 0 ? 0 : (xx > 31 ? 31 : xx))) * CC + cg * 8;
    sidx[j] = sp_p * 32 + (((cg + (sp_p >> 1)) & 3) << 3);
  }

  const short* wlane = Wp + ((size_t)(t * 4 + cb) * 8 * 9 * 4) * 512 + lane * 8;
  // fragment offset: ((kc*9+tap)*4+nt)*512

  f32x4 acc[2][4];
#pragma unroll
  for (int mt = 0; mt < 2; ++mt)
#pragma unroll
    for (int nt = 0; nt < 4; ++nt) acc[mt][nt] = (f32x4){0.f, 0.f, 0.f, 0.f};

  bf16x8 zerov = {0, 0, 0, 0, 0, 0, 0, 0};
  bf16x8 ipf[4];
#pragma unroll
  for (int j = 0; j < 4; ++j)
    ipf[j] = iact[j] ? *(const bf16x8*)(inb + ioff[j]) : zerov;

  bf16x8 Bw[2][4];
#pragma unroll
  for (int nt = 0; nt < 4; ++nt)
    Bw[0][nt] = *(const bf16x8*)(wlane + (size_t)nt * 512);

  int pb = 0;
  for (int kc = 0; kc < 8; ++kc) {
    int ci0 = kc << 5;
    __syncthreads();   // previous chunk's readers done
#pragma unroll
    for (int j = 0; j < 4; ++j)
      if (ivalid[j]) *(bf16x8*)(sI + sidx[j]) = ipf[j];
    __syncthreads();
    if (kc < 7) {
#pragma unroll
      for (int j = 0; j < 4; ++j)
        ipf[j] = iact[j] ? *(const bf16x8*)(inb + ioff[j] + ci0 + 32) : zerov;
    }

#pragma unroll
    for (int tap = 0; tap < 9; ++tap) {
      int nb = pb ^ 1;
      // prefetch next tap's (or next chunk's tap0) weight fragments
      if (!(kc == 7 && tap == 8)) {
        int nkc = (tap == 8) ? kc + 1 : kc;
        int ntap = (tap == 8) ? 0 : tap + 1;
        size_t fo = (size_t)((nkc * 9 + ntap) * 4) * 512;
#pragma unroll
        for (int nt = 0; nt < 4; ++nt)
          Bw[nb][nt] = *(const bf16x8*)(wlane + fo + (size_t)nt * 512);
      }
      bf16x8 Af[2];
#pragma unroll
      for (int mt = 0; mt < 2; ++mt) {
        int sp_p = pbA[mt] + dtap[tap];
        Af[mt] = *(const bf16x8*)(sI + sp_p * 32 + (((quad + (sp_p >> 1)) & 3) << 3));
      }
#pragma unroll
      for (int mt = 0; mt < 2; ++mt)
#pragma unroll
        for (int nt = 0; nt < 4; ++nt)
          acc[mt][nt] = __builtin_amdgcn_mfma_f32_16x16x32_bf16(Af[mt], Bw[pb][nt],
                                                                acc[mt][nt], 0, 0, 0);
      pb = nb;
    }
  }

  // token-major bf16 stores
  size_t tb = (size_t)t * 8192 + b * 1024 + r0 * 32;
#pragma unroll
  for (int mt = 0; mt < 2; ++mt)
#pragma unroll
    for (int nt = 0; nt < 4; ++nt)
#pragma unroll
      for (int r = 0; r < 4; ++r) {
        int sp = w * 32 + mt * 16 + quad * 4 + r;
        ch[(tb + sp) * CC + co0 + nt * 16 + mm] = (short)f2bf(acc[mt][nt][r]);
      }

  // BN stats from fp32 accumulators
  float s[4], q[4];
#pragma unroll
  for (int nt = 0; nt < 4; ++nt) {
    float ss = 0.f, qq = 0.f;
#pragma unroll
    for (int mt = 0; mt < 2; ++mt)
#pragma unroll
      for (int r = 0; r < 4; ++r) {
        float v = acc[mt][nt][r];
        ss += v;
        qq += v * v;
      }
    ss += __shfl_xor(ss, 16); ss += __shfl_xor(ss, 32);
    qq += __shfl_xor(qq, 16); qq += __shfl_xor(qq, 32);
    s[nt] = ss; q[nt] = qq;
  }
  if (quad == 0) {
#pragma unroll
    for (int nt = 0; nt < 4; ++nt) {
      sws[w][nt * 16 + mm] = s[nt];
      swq[w][nt * 16 + mm] = q[nt];
    }
  }
  __syncthreads();
  if (tid < 64) {
    float S = sws[0][tid] + sws[1][tid] + sws[2][tid] + sws[3][tid];
    float Q = swq[0][tid] + swq[1][tid] + swq[2][tid] + swq[3][tid];
    atomicAdd(&st[t * 512 + co0 + tid], S);
    atomicAdd(&st[t * 512 + 256 + co0 + tid], Q);
  }
}

// ---------------- fold BN into proj weights -> bf16 hi/lo + fp32 bias ----------------
__global__ __launch_bounds__(256) void k_fuse(const float* __restrict__ Wq,
                                              const float* __restrict__ Wk,
                                              const float* __restrict__ Wv,
                                              const float* __restrict__ gq,
                                              const float* __restrict__ gk,
                                              const float* __restrict__ gv,
                                              const float* __restrict__ bq,
                                              const float* __restrict__ bk,
                                              const float* __restrict__ bv,
                                              const float* __restrict__ st,
                                              short* __restrict__ Wfh,
                                              short* __restrict__ Wfl,
                                              float* __restrict__ bfv) {
  int t = blockIdx.y;
  const float* W = t == 0 ? Wq : (t == 1 ? Wk : Wv);
  const float* gamma = t == 0 ? gq : (t == 1 ? gk : gv);
  const float* beta = t == 0 ? bq : (t == 1 ? bk : bv);
  int co = blockIdx.x, ci = threadIdx.x;
  float mu = st[t * 512 + ci] * (1.f / 8192.f);
  float var = st[t * 512 + 256 + ci] * (1.f / 8192.f) - mu * mu;
  float a = gamma[ci] * rsqrtf(var + EPSBN);
  float dt = beta[ci] - mu * a;
  float wv = W[co * CC + ci];
  float v = wv * a;
  unsigned short hh = f2bf(v);
  Wfh[(size_t)t * 65536 + co * CC + ci] = (short)hh;
  Wfl[(size_t)t * 65536 + co * CC + ci] = (short)f2bf(v - bf2f(hh));
  __shared__ float red[256];
  red[ci] = dt * wv;
  __syncthreads();
  for (int s2 = 128; s2 > 0; s2 >>= 1) {
    if (ci < s2) red[ci] += red[ci + s2];
    __syncthreads();
  }
  if (ci == 0) bfv[t * 256 + co] = red[0];
}

// ---------------- projections (fused q/k/v), register-stationary B ----------------
// Q,K written HEAD-MAJOR [(b*8+h)][1024][32] (Q pre-scaled by QSCALE*log2e);
// V written feature-major with t' interleave (t' = 16*quad+4*r+(g&3)).
__global__ __launch_bounds__(256, 2) void k_proj(const short* __restrict__ ch,
                                                 const short* __restrict__ Wfh,
                                                 const short* __restrict__ Wfl,
                                                 const float* __restrict__ bfv,
                                                 short* __restrict__ Qh,
                                                 short* __restrict__ Kh,
                                                 short* __restrict__ Vh) {
  __shared__ __align__(16) short sT[64 * 264];   // V transpose buffer
  int tid = threadIdx.x;
  int t = blockIdx.z;
  int t0 = blockIdx.x << 8;
  int co0 = blockIdx.y << 6;
  int lane = tid & 63, w = tid >> 6;
  int quad = lane >> 4, mm = lane & 15;
  int colw = co0 + w * 16;
  const short* cht = ch + (size_t)t * 8192 * CC;

  bf16x8 Bh[8], Bl[8];
  {
    const short* bh = Wfh + (size_t)t * 65536 + (size_t)(colw + mm) * CC + quad * 8;
    const short* bl = Wfl + (size_t)t * 65536 + (size_t)(colw + mm) * CC + quad * 8;
#pragma unroll
    for (int kc = 0; kc < 8; ++kc) {
      Bh[kc] = *(const bf16x8*)(bh + kc * 32);
      Bl[kc] = *(const bf16x8*)(bl + kc * 32);
    }
  }
  float bv = bfv[t * 256 + colw + mm];

  int c = colw + mm;
  int hh = c >> 5, dd = c & 31;
  int bb = t0 >> 10, lbase = t0 & 1023;
  size_t hb = (size_t)(bb * 8 + hh) * 1024;

  bf16x8 A0[8], A1[8];
  auto loadA = [&](bf16x8* dst, int g) {
    const short* a = cht + (size_t)(t0 + g * 16 + mm) * CC + quad * 8;
#pragma unroll
    for (int kc = 0; kc < 8; ++kc) dst[kc] = *(const bf16x8*)(a + kc * 32);
  };
  auto compute = [&](const bf16x8* A, int g) {
    f32x4 aH = {0.f, 0.f, 0.f, 0.f}, aL = {0.f, 0.f, 0.f, 0.f};
#pragma unroll
    for (int kc = 0; kc < 8; ++kc) {
      aH = __builtin_amdgcn_mfma_f32_16x16x32_bf16(A[kc], Bh[kc], aH, 0, 0, 0);
      aL = __builtin_amdgcn_mfma_f32_16x16x32_bf16(A[kc], Bl[kc], aL, 0, 0, 0);
    }
    if (t == 0) {
#pragma unroll
      for (int r = 0; r < 4; ++r) {
        int l = lbase + g * 16 + quad * 4 + r;
        Qh[(hb + l) * 32 + dd] = (short)f2bf((aH[r] + aL[r] + bv) * SCLOG2E);
      }
    } else if (t == 1) {
#pragma unroll
      for (int r = 0; r < 4; ++r) {
        int l = lbase + g * 16 + quad * 4 + r;
        Kh[(hb + l) * 32 + dd] = (short)f2bf(aH[r] + aL[r] + bv);
      }
    } else {
#pragma unroll
      for (int r = 0; r < 4; ++r)
        sT[(w * 16 + mm) * 264 + (g >> 2) * 64 + 16 * quad + 4 * r + (g & 3)] =
            (short)f2bf(aH[r] + aL[r] + bv);
    }
  };

  loadA(A0, 0);
#pragma unroll
  for (int g = 0; g < 16; g += 2) {
    loadA(A1, g + 1);
    compute(A0, g);
    if (g + 2 < 16) loadA(A0, g + 2);
    compute(A1, g + 1);
  }

  if (t == 2) {
    __syncthreads();
    int b = t0 >> 10, l0 = t0 & 1023;
#pragma unroll
    for (int j = 0; j < 8; ++j) {
      int idx = tid + (j << 8);
      int co = idx >> 5, tg = idx & 31;
      bf16x8 v = *(const bf16x8*)(sT + co * 264 + tg * 8);
      *(bf16x8*)(Vh + ((size_t)(b * CC) + co0 + co) * LLEN + l0 + tg * 8) = v;
    }
  }
}

// ---------------- flash attention v5: head-major Q/K, conflict-free sK ----------------
// grid (64 = b*8+h, 8 q-tiles), block 256: 4 waves x 32 q-rows.
__global__ __launch_bounds__(256, 2) void k_attn(const short* __restrict__ Qh,
                                                 const short* __restrict__ Kh,
                                                 const short* __restrict__ Vh,
                                                 short* __restrict__ AOh) {
  __shared__ __align__(16) short sK[2][64 * 40];   // [t][d] stride 40 (2-way free)
  __shared__ __align__(16) short sV[2][32 * 72];   // [d][t'] stride 72
  __shared__ __align__(16) short sP[4 * 32 * 72];  // per-wave [q][t'] stride 72

  int tid = threadIdx.x;
  int lane = tid & 63, w = tid >> 6;
  int quad = lane >> 4, mm = lane & 15;
  int bh = blockIdx.x;
  int b = bh >> 3, h = bh & 7;
  int l0 = blockIdx.y << 7;

  bf16x8 qf[2];
#pragma unroll
  for (int mf = 0; mf < 2; ++mf)
    qf[mf] = *(const bf16x8*)(Qh + ((size_t)bh * 1024 + l0 + w * 32 + mf * 16 + mm) * 32 +
                              quad * 8);

  f32x4 accO[2][2], accL[2];
#pragma unroll
  for (int mf = 0; mf < 2; ++mf) {
    accO[mf][0] = (f32x4){0.f, 0.f, 0.f, 0.f};
    accO[mf][1] = (f32x4){0.f, 0.f, 0.f, 0.f};
    accL[mf] = (f32x4){0.f, 0.f, 0.f, 0.f};
  }
  bf16x8 ones;
#pragma unroll
  for (int j = 0; j < 8; ++j) ones[j] = (short)0x3F80;  // bf16 1.0

  int kt = tid >> 2, kc4 = tid & 3;
  const short* kgp = Kh + ((size_t)bh * 1024 + kt) * 32 + kc4 * 8;
  int kofs = kt * 40 + kc4 * 8;
  int vd = tid >> 3, vt8 = tid & 7;
  const short* vgp = Vh + ((size_t)(b * CC) + h * HD + vd) * LLEN + vt8 * 8;
  int vofs = vd * 72 + vt8 * 8;
  short* pw = sP + w * (32 * 72);

  bf16x8 kr = *(const bf16x8*)kgp;
  bf16x8 vr = *(const bf16x8*)vgp;
  *(bf16x8*)(sK[0] + kofs) = kr;
  *(bf16x8*)(sV[0] + vofs) = vr;
  __syncthreads();

  for (int tt = 0; tt < 16; ++tt) {
    if (tt < 15) {
      kr = *(const bf16x8*)(kgp + (size_t)(tt + 1) * 64 * 32);
      vr = *(const bf16x8*)(vgp + (tt + 1) * 64);
    }
    const short* sKc = sK[tt & 1];
    const short* sVc = sV[tt & 1];

#pragma unroll
    for (int mf = 0; mf < 2; ++mf) {
      f32x4 accS[4];
#pragma unroll
      for (int nt = 0; nt < 4; ++nt) {
        bf16x8 kf = *(const bf16x8*)(sKc + (nt * 16 + mm) * 40 + quad * 8);
        f32x4 z = {0.f, 0.f, 0.f, 0.f};
        accS[nt] = __builtin_amdgcn_mfma_f32_16x16x32_bf16(qf[mf], kf, z, 0, 0, 0);
      }
#pragma unroll
      for (int r = 0; r < 4; ++r) {
        int q = mf * 16 + quad * 4 + r;
        bf16x4 pk;
#pragma unroll
        for (int nt = 0; nt < 4; ++nt) {
          union { float f; unsigned u; } cv;
          cv.f = __builtin_exp2f(accS[nt][r]);
          pk[nt] = (short)((cv.u + 0x8000u) >> 16);
        }
        *(bf16x4*)(pw + q * 72 + mm * 4) = pk;
      }
    }

#pragma unroll
    for (int kc = 0; kc < 2; ++kc) {
      bf16x8 vf0 = *(const bf16x8*)(sVc + mm * 72 + kc * 32 + quad * 8);
      bf16x8 vf1 = *(const bf16x8*)(sVc + (16 + mm) * 72 + kc * 32 + quad * 8);
#pragma unroll
      for (int mf = 0; mf < 2; ++mf) {
        bf16x8 pf = *(const bf16x8*)(pw + (mf * 16 + mm) * 72 + kc * 32 + quad * 8);
        accL[mf] = __builtin_amdgcn_mfma_f32_16x16x32_bf16(pf, ones, accL[mf], 0, 0, 0);
        accO[mf][0] = __builtin_amdgcn_mfma_f32_16x16x32_bf16(pf, vf0, accO[mf][0], 0, 0, 0);
        accO[mf][1] = __builtin_amdgcn_mfma_f32_16x16x32_bf16(pf, vf1, accO[mf][1], 0, 0, 0);
      }
    }

    if (tt < 15) {
      __syncthreads();
      *(bf16x8*)(sK[(tt + 1) & 1] + kofs) = kr;
      *(bf16x8*)(sV[(tt + 1) & 1] + vofs) = vr;
      __syncthreads();
    }
  }

#pragma unroll
  for (int mf = 0; mf < 2; ++mf)
#pragma unroll
    for (int r = 0; r < 4; ++r) {
      float inv = __builtin_amdgcn_rcpf(accL[mf][r]);
      size_t token = (size_t)(b * LLEN) + l0 + w * 32 + mf * 16 + quad * 4 + r;
      AOh[token * CC + h * HD + mm] = (short)f2bf(accO[mf][0][r] * inv);
      AOh[token * CC + h * HD + 16 + mm] = (short)f2bf(accO[mf][1][r] * inv);
    }
}

// ---------------- output GEMM, register-stationary B, fp32 out ----------------
__global__ __launch_bounds__(256, 2) void k_out(const short* __restrict__ AOh,
                                                const short* __restrict__ Woh,
                                                const short* __restrict__ Wol,
                                                const float* __restrict__ bo,
                                                float* __restrict__ out) {
  int tid = threadIdx.x;
  int t0 = blockIdx.x << 7;
  int co0 = blockIdx.y << 6;
  int lane = tid & 63, w = tid >> 6;
  int quad = lane >> 4, mm = lane & 15;
  int colw = co0 + w * 16;

  bf16x8 Bh[8], Bl[8];
  {
    const short* bh = Woh + (size_t)(colw + mm) * CC + quad * 8;
    const short* bl = Wol + (size_t)(colw + mm) * CC + quad * 8;
#pragma unroll
    for (int kc = 0; kc < 8; ++kc) {
      Bh[kc] = *(const bf16x8*)(bh + kc * 32);
      Bl[kc] = *(const bf16x8*)(bl + kc * 32);
    }
  }
  float bv = bo[colw + mm];

  bf16x8 A0[8], A1[8];
  auto loadA = [&](bf16x8* dst, int g) {
    const short* a = AOh + (size_t)(t0 + g * 16 + mm) * CC + quad * 8;
#pragma unroll
    for (int kc = 0; kc < 8; ++kc) dst[kc] = *(const bf16x8*)(a + kc * 32);
  };
  auto compute = [&](const bf16x8* A, int g) {
    f32x4 aH = {0.f, 0.f, 0.f, 0.f}, aL = {0.f, 0.f, 0.f, 0.f};
#pragma unroll
    for (int kc = 0; kc < 8; ++kc) {
      aH = __builtin_amdgcn_mfma_f32_16x16x32_bf16(A[kc], Bh[kc], aH, 0, 0, 0);
      aL = __builtin_amdgcn_mfma_f32_16x16x32_bf16(A[kc], Bl[kc], aL, 0, 0, 0);
    }
#pragma unroll
    for (int r = 0; r < 4; ++r) {
      int token = t0 + g * 16 + quad * 4 + r;
      out[(size_t)token * CC + colw + mm] = aH[r] + aL[r] + bv;
    }
  };

  loadA(A0, 0);
#pragma unroll
  for (int g = 0; g < 8; g += 2) {
    loadA(A1, g + 1);
    compute(A0, g);
    if (g + 2 < 8) loadA(A0, g + 2);
    compute(A1, g + 1);
  }
}

extern "C" void kernel_launch(void* const* d_in, const int* in_sizes, int n_in,
                              void* d_out, int out_size, void* d_ws, size_t ws_size,
                              hipStream_t stream) {
  (void)in_sizes; (void)n_in; (void)out_size; (void)ws_size;
  const float* x  = (const float*)d_in[0];
  const float* y  = (const float*)d_in[1];
  const float* wq = (const float*)d_in[4];
  const float* gq = (const float*)d_in[5];
  const float* bq = (const float*)d_in[6];
  const float* wk = (const float*)d_in[7];
  const float* gk = (const float*)d_in[8];
  const float* bk = (const float*)d_in[9];
  const float* wv = (const float*)d_in[10];
  const float* gv = (const float*)d_in[11];
  const float* bv = (const float*)d_in[12];
  const float* Wq = (const float*)d_in[13];
  const float* Wk = (const float*)d_in[14];
  const float* Wv = (const float*)d_in[15];
  const float* Wo = (const float*)d_in[16];
  const float* bo = (const float*)d_in[17];
  float* out = (float*)d_out;

  const size_t NP = (size_t)8192 * 256;  // one bf16 plane = 2M shorts
  short* xh  = (short*)d_ws;
  short* yh  = xh + NP;
  short* ch  = yh + NP;            // conv-hi [3] planes
  short* Qh  = ch + 3 * NP;        // head-major [64][1024][32]
  short* Kh  = Qh + NP;            // head-major
  short* Vh  = Kh + NP;            // feature-major, t'-interleaved
  short* AOh = Vh + NP;
  short* Wp  = AOh + NP;           // packed conv weights [3][4][8][9][4][512]
  short* Wfh = Wp + (size_t)3 * 9 * 65536;
  short* Wfl = Wfh + 3 * 65536;
  short* Woh = Wfl + 3 * 65536;
  short* Wol = Woh + 65536;
  float* st  = (float*)(Wol + 65536);  // 3 x (sum256 + sumsq256)
  float* bfv = st + 1536;              // 3 x 256 fused bias

  hipMemsetAsync(st, 0, 1536 * sizeof(float), stream);

  k_prep<<<5120, 256, 0, stream>>>(x, y, wq, wk, wv, Wo, xh, yh, Wp, Woh, Wol);

  k_conv<<<dim3(4, 8, 24), 256, 0, stream>>>(xh, yh, Wp, ch, st);

  k_fuse<<<dim3(256, 3), 256, 0, stream>>>(Wq, Wk, Wv, gq, gk, gv, bq, bk, bv,
                                           st, Wfh, Wfl, bfv);

  k_proj<<<dim3(32, 4, 3), 256, 0, stream>>>(ch, Wfh, Wfl, bfv, Qh, Kh, Vh);

  k_attn<<<dim3(64, 8), 256, 0, stream>>>(Qh, Kh, Vh, AOh);

  k_out<<<dim3(64, 4), 256, 0, stream>>>(AOh, Woh, Wol, bo, out);
}